// Round 4
// baseline (1143.825 us; speedup 1.0000x reference)
//
#include <hip/hip_runtime.h>

// GRU encoder: B=64, T=256, U=1024, VOCAB=10000. All float tensors are FP32.
// GEMM on bf16 MFMA (RNE-converted inputs); h carry stays exact f32 in a
// per-thread register. ONE persistent kernel; W_rec fragments resident in
// registers for all 256 steps.
//
// Round-4 change: the cross-block step handoff is a SINGLE-WORD tagged
// publish. Each h element is stored as u32 {step_tag:16 | bf16(h):16} with
// sc0 sc1 write-through (fire-and-forget, NO drain, NO flag, NO release).
// Consumers poll the A-operand data itself until every dword carries the
// expected tag — word atomicity makes tag+payload indivisible, so no
// ordering/fence is needed anywhere. This collapses the step chain from
// three serialized LLC round-trips (h-drain, flag, A-load) to one.
// hbuf is parity-double-buffered; tags (=step) disambiguate t vs t-2.
#define BB 64
#define TT 256
#define UU 1024
#define NG 3072

typedef __attribute__((ext_vector_type(8))) __bf16 bf16x8;
typedef __attribute__((ext_vector_type(4))) float f32x4;

__device__ __forceinline__ unsigned short f2bf(float f) {
    union { unsigned int i; float f; } c; c.f = f;
    unsigned int r = c.i + 0x7FFFu + ((c.i >> 16) & 1u);  // RNE
    return (unsigned short)(r >> 16);
}

union U16x8 { unsigned short us[8]; uint4 u4; };

// ---------------------------------------------------------------------------
// Pack W_rec (f32) into bf16 MFMA B-fragment order (unchanged, verified).
// Total 6 MB.
// ---------------------------------------------------------------------------
__global__ __launch_bounds__(256) void pack_kernel(
    const float* __restrict__ w_rec,    // (1024, 3072) f32
    uint4* __restrict__ wpack)
{
    const int tid  = threadIdx.x;
    const int kc   = tid >> 6;
    const int lane = tid & 63;
    const int l16  = lane & 15;
    const int quad = lane >> 4;
    const int cj   = blockIdx.x;            // 0..63
    const int colb = (cj << 4) + l16;

    #pragma unroll
    for (int g = 0; g < 3; ++g) {
        #pragma unroll
        for (int s = 0; s < 8; ++s) {
            const int kb = (kc << 8) + (s << 5) + (quad << 3);
            U16x8 c;
            #pragma unroll
            for (int j = 0; j < 8; ++j)
                c.us[j] = f2bf(w_rec[(size_t)(kb + j) * NG + g * UU + colb]);
            wpack[(size_t)(((cj * 4 + kc) * 24) + g * 8 + s) * 64 + lane] = c.u4;
        }
    }
}

// Seed: parity 0 = {tag 0 | bf16(hidden)}; parity 1 poisoned with tag 0xFFFF
// so graph replays never see a stale matching tag.
__global__ __launch_bounds__(256) void seed_kernel(
    const float* __restrict__ hidden,       // (64, 1024) f32
    unsigned int* __restrict__ hbuf32)
{
    const int i = blockIdx.x * 256 + threadIdx.x;   // 65536 elements
    hbuf32[i] = (unsigned int)f2bf(hidden[i]);      // tag 0 in high half
    hbuf32[BB * UU + i] = 0xFFFF0000u;              // invalid tag
}

// ---------------------------------------------------------------------------
// Persistent GRU kernel. 256 blocks x 256 threads, 1 block/CU.
// block = (ri, cj): ri = batch rowgroup (4 x 16 rows), cj = unit colgroup
// (64 x 16 cols). Waves K-split (4 x 256). Step t consumes parity t&1 words
// tagged t; step t produces parity (t+1)&1 words tagged t+1.
// ---------------------------------------------------------------------------
__global__ __launch_bounds__(256) void gru_kernel(
    const int* __restrict__ x,              // (64, 256) int32
    const float* __restrict__ hidden,       // (64, 1024) f32
    const float* __restrict__ w_in,         // (10000, 3072) f32
    const float* __restrict__ b_in,         // (3072,) f32
    const float* __restrict__ b_rec,        // (3072,) f32
    const uint4* __restrict__ wpack,        // packed W_rec bf16 frags
    float* __restrict__ out,                // (64,256,1024) + (64,1024) f32
    unsigned int* __restrict__ hbuf32)      // ws: 2 x 64 x 1024 tagged u32
{
    const int tid  = threadIdx.x;
    const int wave = tid >> 6;        // K-chunk 0..3
    const int lane = tid & 63;
    const int l16  = lane & 15;
    const int quad = lane >> 4;

    const int ri   = blockIdx.x >> 6;  // 0..3
    const int cj   = blockIdx.x & 63;  // 0..63
    const int row0 = ri << 4;
    const int col0 = cj << 4;

    // parity-double-buffered K-reduction scratch (removes the 2nd barrier)
    __align__(16) __shared__ float red[2][4][3][64][4];   // 24 KB

    // ---- B-fragments: loaded ONCE, resident for all 256 steps ----
    const uint4* wp = wpack + (size_t)((cj * 4 + wave) * 24) * 64 + lane;
    uint4 wf[3][8];
    #pragma unroll
    for (int g = 0; g < 3; ++g)
        #pragma unroll
        for (int s = 0; s < 8; ++s)
            wf[g][s] = wp[(g * 8 + s) * 64];

    // ---- per-thread gate element (fixed for the whole sequence) ----
    const int em = tid >> 4;
    const int en = tid & 15;
    const int gb = row0 + em;
    const int gu = col0 + en;
    // C/D layout (col=lane&15, row=(lane>>4)*4+reg) -> source lane/reg
    const int rl = ((em >> 2) << 4) | en;
    const int rr = em & 3;

    // loop-invariant biases
    const float bz  = b_in[gu]          + b_rec[gu];
    const float br  = b_in[UU + gu]     + b_rec[UU + gu];
    const float bih = b_in[2 * UU + gu];
    const float brh = b_rec[2 * UU + gu];

    // exact f32 h carry in a register
    float h = hidden[gb * UU + gu];

    const int* xrow = x + gb * TT;

    const unsigned int* a0 = hbuf32 + (size_t)(row0 + l16) * UU
                           + (wave << 8) + (quad << 3);         // parity 0 A base
    const unsigned int* a1 = a0 + (size_t)BB * UU;              // parity 1
    unsigned int* hb0 = hbuf32 + (size_t)gb * UU + gu;          // parity 0 slot
    unsigned int* hb1 = hb0 + (size_t)BB * UU;                  // parity 1
    float* orow = out + (size_t)gb * TT * UU + gu;

    // embedding gather for t=0 (plain cached loads)
    size_t wrow = (size_t)xrow[0] * NG;
    float wz = w_in[wrow + gu];
    float wr = w_in[wrow + UU + gu];
    float wh = w_in[wrow + 2 * UU + gu];

    for (int t = 0; t < TT; ++t) {
        // ---- data-poll: load A words (u32 tagged), retry until every dword
        // of this wave's K-slice carries tag == t. sc0 sc1 bypasses stale
        // L1/L2 and reads the LLC where producers wrote through. ----
        const unsigned int texp = (unsigned int)t << 16;
        const unsigned int* arow = (t & 1) ? a1 : a0;
        uint4 q[16];
        for (;;) {
            #pragma unroll
            for (int s = 0; s < 8; ++s) {
                asm volatile("global_load_dwordx4 %0, %1, off sc0 sc1"
                             : "=v"(q[2 * s])     : "v"(arow + (s << 5)));
                asm volatile("global_load_dwordx4 %0, %1, off sc0 sc1"
                             : "=v"(q[2 * s + 1]) : "v"(arow + (s << 5) + 4));
            }
            asm volatile("s_waitcnt vmcnt(0)" ::: "memory");
            unsigned int acc = 0;
            #pragma unroll
            for (int i = 0; i < 16; ++i)
                acc |= (q[i].x ^ texp) | (q[i].y ^ texp)
                     | (q[i].z ^ texp) | (q[i].w ^ texp);
            if (__all((acc & 0xFFFF0000u) == 0u)) break;
        }
        __builtin_amdgcn_sched_barrier(0);

        // ---- pack low halves (bf16 h) into MFMA A fragments + MFMA ----
        f32x4 acc0 = {0.f, 0.f, 0.f, 0.f};
        f32x4 acc1 = {0.f, 0.f, 0.f, 0.f};
        f32x4 acc2 = {0.f, 0.f, 0.f, 0.f};
        #pragma unroll
        for (int s = 0; s < 8; ++s) {
            const uint4 lo = q[2 * s];
            const uint4 hi = q[2 * s + 1];
            uint4 aw;
            aw.x = (lo.x & 0xFFFFu) | (lo.y << 16);
            aw.y = (lo.z & 0xFFFFu) | (lo.w << 16);
            aw.z = (hi.x & 0xFFFFu) | (hi.y << 16);
            aw.w = (hi.z & 0xFFFFu) | (hi.w << 16);
            const bf16x8 a = __builtin_bit_cast(bf16x8, aw);
            acc0 = __builtin_amdgcn_mfma_f32_16x16x32_bf16(
                a, __builtin_bit_cast(bf16x8, wf[0][s]), acc0, 0, 0, 0);
            acc1 = __builtin_amdgcn_mfma_f32_16x16x32_bf16(
                a, __builtin_bit_cast(bf16x8, wf[1][s]), acc1, 0, 0, 0);
            acc2 = __builtin_amdgcn_mfma_f32_16x16x32_bf16(
                a, __builtin_bit_cast(bf16x8, wf[2][s]), acc2, 0, 0, 0);
        }

        // ---- cross-wave K reduction through LDS (parity-buffered) ----
        const int p = t & 1;
        *(f32x4*)&red[p][wave][0][lane][0] = acc0;
        *(f32x4*)&red[p][wave][1][lane][0] = acc1;
        *(f32x4*)&red[p][wave][2][lane][0] = acc2;
        __syncthreads();

        const float rz = red[p][0][0][rl][rr] + red[p][1][0][rl][rr]
                       + red[p][2][0][rl][rr] + red[p][3][0][rl][rr];
        const float rrv = red[p][0][1][rl][rr] + red[p][1][1][rl][rr]
                        + red[p][2][1][rl][rr] + red[p][3][1][rl][rr];
        const float rh = red[p][0][2][rl][rr] + red[p][1][2][rl][rr]
                       + red[p][2][2][rl][rr] + red[p][3][2][rl][rr];

        const float z  = 1.f / (1.f + expf(-(wz + rz + bz)));
        const float r  = 1.f / (1.f + expf(-(wr + rrv + br)));
        const float hh = tanhf(wh + bih + r * (rh + brh));
        h = z * h + (1.f - z) * hh;

        // ---- publish FIRST (critical path): single tagged word, no drain ----
        if (t < TT - 1) {
            const unsigned int hv = ((unsigned int)(t + 1) << 16)
                                  | (unsigned int)f2bf(h);
            unsigned int* hs = (t & 1) ? hb0 : hb1;   // parity (t+1)&1
            asm volatile("global_store_dword %0, %1, off sc0 sc1"
                         :: "v"(hs), "v"(hv) : "memory");
        }

        // ---- background: out row + next embedding gather (off the chain) ----
        orow[(size_t)t * UU] = h;
        if (t < TT - 1) {
            wrow = (size_t)xrow[t + 1] * NG;
            wz = w_in[wrow + gu];
            wr = w_in[wrow + UU + gu];
            wh = w_in[wrow + 2 * UU + gu];
        }
    }

    // final state
    out[(size_t)BB * TT * UU + (size_t)gb * UU + gu] = h;
}

extern "C" void kernel_launch(void* const* d_in, const int* in_sizes, int n_in,
                              void* d_out, int out_size, void* d_ws, size_t ws_size,
                              hipStream_t stream) {
    const int* x        = (const int*)d_in[0];
    const float* hidden = (const float*)d_in[1];
    const float* w_in   = (const float*)d_in[2];
    const float* w_rec  = (const float*)d_in[3];
    const float* b_in   = (const float*)d_in[4];
    const float* b_rec  = (const float*)d_in[5];
    float* out          = (float*)d_out;

    unsigned char* ws = (unsigned char*)d_ws;
    uint4* wpack          = (uint4*)ws;                        // 6 MB
    unsigned int* hbuf32  = (unsigned int*)(ws + 6291456);     // 512 KB tagged
    // total ws requirement: 6815744 bytes (~6.5 MiB)

    pack_kernel<<<64, 256, 0, stream>>>(w_rec, wpack);
    seed_kernel<<<256, 256, 0, stream>>>(hidden, hbuf32);
    gru_kernel<<<256, 256, 0, stream>>>(x, hidden, w_in, b_in, b_rec,
                                        wpack, out, hbuf32);
}